// Round 3
// baseline (263.713 us; speedup 1.0000x reference)
//
#include <hip/hip_runtime.h>
#include <hip/hip_cooperative_groups.h>
#include <stdint.h>

namespace cg = cooperative_groups;

// Problem geometry (fixed by reference):
//   preds      [8, 21, 512, 512] f32
//   embeddings [8, 128, 128, 128] f32
//   gts        [8, 512, 512] i32  (unused)
//   fsss_gts   [8, 512, 512] i32
//   pos_memory [1000, 128] f32
//   neg_memory [1000, 128] f32
//   out: scalar f32
// Downsample 512->128 nearest picks rows/cols 4i, 4j exactly.

#define NBLK  512      // grid blocks; also 131072/256
#define MEMSZ 1000
#define KANC  100      // MEM/10
#define KPN   333      // MEM/3
#define SLOT_POS 100
#define SLOT_NEG 433
#define NSLOTS 766

__global__ __launch_bounds__(256, 2) void fused_kernel(
    const float* __restrict__ preds,
    const float* __restrict__ emb,
    const int* __restrict__ fsss,
    const float* __restrict__ posMem,
    const float* __restrict__ negMem,
    float* __restrict__ out,
    int* __restrict__ blockCounts,   // 3*512
    int* __restrict__ idx,           // 768
    float* __restrict__ Esel,        // 766*128
    float* __restrict__ partials)    // 17*128
{
    cg::grid_group grid = cg::this_grid();
    const int tid = threadIdx.x;
    const int blk = blockIdx.x;
    const int lane = tid & 63;
    const int wave = tid >> 6;

    __shared__ int s_i[16];
    __shared__ int s_off[3];
    __shared__ int s_tot[3];
    __shared__ float s_f[4];
    __shared__ double s_d[2];

    // ================= P1: argmax + masks + per-block counts =================
    const int n = blk * 256 + tid;          // flat position, n < 131072
    const int b = n >> 14;
    const int ij = n & 16383;
    const int row = ((ij >> 7) << 2);       // 4*i
    const int col = ((ij & 127) << 2);      // 4*j

    const float* p = preds + (size_t)b * 21 * 262144 + (size_t)row * 512 + col;
    float best = p[0];
    int bc = 0;
#pragma unroll
    for (int c = 1; c < 21; ++c) {
        float v = p[(size_t)c * 262144];
        if (v > best) { best = v; bc = c; }   // strict > = first-max (jnp.argmax)
    }
    const int fv = fsss[(size_t)b * 262144 + (size_t)row * 512 + col];

    const bool pm = (bc != 0);
    const bool fm = (fv != 0) && (fv != 255);
    const int myflag = (int)(pm && fm)                // anchor
                     | ((int)(!pm && fm) << 1)        // positive
                     | ((int)(pm && (fv == 0)) << 2); // negative

#pragma unroll
    for (int cat = 0; cat < 3; ++cat) {
        unsigned long long m = __ballot((myflag >> cat) & 1);
        if (lane == 0) s_i[cat * 4 + wave] = (int)__popcll(m);
    }
    __syncthreads();
    if (tid < 3)
        blockCounts[tid * NBLK + blk] =
            s_i[tid * 4] + s_i[tid * 4 + 1] + s_i[tid * 4 + 2] + s_i[tid * 4 + 3];

    grid.sync();

    // ======== P2: every block redundantly scans the 3x512 block counts ========
    // thread t owns elements 2t and 2t+1 (512 elements, 256 threads)
#pragma unroll 1
    for (int cat = 0; cat < 3; ++cat) {
        const int c0 = blockCounts[cat * NBLK + 2 * tid];
        const int c1 = blockCounts[cat * NBLK + 2 * tid + 1];
        const int sum2 = c0 + c1;
        int incl = sum2;
#pragma unroll
        for (int off = 1; off < 64; off <<= 1) {
            int v = __shfl_up(incl, off, 64);
            if (lane >= off) incl += v;
        }
        if (lane == 63) s_i[wave] = incl;
        __syncthreads();
        int woff = 0;
#pragma unroll
        for (int w = 0; w < 4; ++w) if (w < wave) woff += s_i[w];
        const int total = s_i[0] + s_i[1] + s_i[2] + s_i[3];
        const int excl0 = woff + incl - sum2;          // exclusive prefix @ elem 2t
        if (tid == (blk >> 1)) s_off[cat] = (blk & 1) ? (excl0 + c0) : excl0;
        if (tid == 0) s_tot[cat] = total;
        __syncthreads();                                // protect s_i reuse
    }
    const int A = min(KANC, s_tot[0]);
    const int P = min(KPN, s_tot[1]);
    const int Q = min(KPN, s_tot[2]);

    // ================= P3: first-k selection (global rank) =================
    unsigned long long masks[3];
#pragma unroll
    for (int cat = 0; cat < 3; ++cat) {
        masks[cat] = __ballot((myflag >> cat) & 1);
        if (lane == 0) s_i[cat * 4 + wave] = (int)__popcll(masks[cat]);
    }
    __syncthreads();
    {
        const int kcap[3] = {KANC, KPN, KPN};
        const int basec[3] = {0, SLOT_POS, SLOT_NEG};
#pragma unroll
        for (int cat = 0; cat < 3; ++cat) {
            if ((myflag >> cat) & 1) {
                int woff = 0;
#pragma unroll
                for (int w = 0; w < 4; ++w) if (w < wave) woff += s_i[cat * 4 + w];
                const int intra = woff + (int)__popcll(masks[cat] & ((1ull << lane) - 1ull));
                const int rank = s_off[cat] + intra;
                if (rank < kcap[cat]) idx[basec[cat] + rank] = n;
            }
        }
    }

    grid.sync();

    // ============ P4: gather + L2-normalize selected rows (2 slots/block) ============
    if (blk < 383) {
        const int half = tid >> 7;       // 0 or 1
        const int d = tid & 127;
        const int slot = blk * 2 + half; // 0..765
        bool valid;
        if (slot < SLOT_POS)      valid = slot < A;
        else if (slot < SLOT_NEG) valid = (slot - SLOT_POS) < P;
        else                      valid = (slot - SLOT_NEG) < Q;

        float v = 0.f;
        if (valid) {
            const int nn = idx[slot];
            const int bb = nn >> 14;
            const int iijj = nn & 16383;
            v = emb[((size_t)bb * 128 + d) * 16384 + iijj];
        }
        float sq = v * v;
#pragma unroll
        for (int off = 1; off < 64; off <<= 1) sq += __shfl_xor(sq, off, 64);
        if (lane == 0) s_f[wave] = sq;   // waves 0,1 = half 0; waves 2,3 = half 1
        __syncthreads();
        const float nrm2 = s_f[half * 2] + s_f[half * 2 + 1];
        if (valid) {
            const float scale = 1.0f / fmaxf(sqrtf(nrm2), 1e-12f);
            Esel[(size_t)slot * 128 + d] = v * scale;
        }
    }

    grid.sync();

    // ================= P5: partial sums (17 blocks) =================
    if (blk < 17 && tid < 128) {
        const int d = tid;
        float acc = 0.f;
        if (blk < 16) {
            const int memSel = blk >> 3;            // 0=pos, 1=neg
            const int part = blk & 7;
            const float* mem = memSel ? negMem : posMem;
            const int cnt = memSel ? Q : P;
            const int baseSlot = memSel ? SLOT_NEG : SLOT_POS;
            const int m0 = part * 125, m1 = m0 + 125;
            for (int m = m0; m < m1; ++m) {
                float v = (m < cnt) ? Esel[(size_t)(baseSlot + m) * 128 + d]
                                    : mem[(size_t)m * 128 + d];
                acc += v;
            }
        } else {
            for (int r = 0; r < A; ++r) acc += Esel[(size_t)r * 128 + d];
        }
        partials[(size_t)blk * 128 + d] = acc;
    }

    grid.sync();

    // ================= P6: final dot + relu (block 0) =================
    if (blk == 0) {
        double prod = 0.0;
        if (tid < 128) {
            const int d = tid;
            float pos = 0.f, neg = 0.f;
#pragma unroll
            for (int pp = 0; pp < 8; ++pp)  pos += partials[pp * 128 + d];
#pragma unroll
            for (int pp = 8; pp < 16; ++pp) neg += partials[pp * 128 + d];
            const float anc = partials[16 * 128 + d];
            prod = (double)anc * ((double)pos - (double)neg);
#pragma unroll
            for (int off = 1; off < 64; off <<= 1) prod += __shfl_xor(prod, off, 64);
        }
        if (tid < 128 && lane == 0) s_d[wave] = prod;
        __syncthreads();
        if (tid == 0) {
            const double red = s_d[0] + s_d[1];
            const double nAnc = (A > 0) ? (double)A : 1.0;
            const double vv = red / (nAnc * (double)MEMSZ) + 0.2;
            out[0] = (float)(vv > 0.0 ? vv : 0.0);
        }
    }
}

extern "C" void kernel_launch(void* const* d_in, const int* in_sizes, int n_in,
                              void* d_out, int out_size, void* d_ws, size_t ws_size,
                              hipStream_t stream) {
    const float* preds  = (const float*)d_in[0];
    const float* emb    = (const float*)d_in[1];
    // d_in[2] = gts, unused by the loss
    const int* fsss     = (const int*)d_in[3];
    const float* posMem = (const float*)d_in[4];
    const float* negMem = (const float*)d_in[5];
    float* out = (float*)d_out;

    char* ws = (char*)d_ws;
    int* blockCounts = (int*)ws;                        // 3*512
    int* idx         = blockCounts + 3 * NBLK;          // 768
    float* Esel      = (float*)(idx + 768);             // 766*128
    float* partials  = Esel + NSLOTS * 128;             // 17*128

    void* args[] = {
        (void*)&preds, (void*)&emb, (void*)&fsss,
        (void*)&posMem, (void*)&negMem, (void*)&out,
        (void*)&blockCounts, (void*)&idx, (void*)&Esel, (void*)&partials
    };
    hipLaunchCooperativeKernel((const void*)fused_kernel,
                               dim3(NBLK), dim3(256), args, 0, stream);
}

// Round 4
// 41.042 us; speedup vs baseline: 6.4255x; 6.4255x over previous
//
#include <hip/hip_runtime.h>
#include <stdint.h>

// Problem geometry (fixed by reference):
//   preds      [8, 21, 512, 512] f32
//   embeddings [8, 128, 128, 128] f32
//   gts        [8, 512, 512] i32  (unused)
//   fsss_gts   [8, 512, 512] i32
//   pos_memory [1000, 128] f32
//   neg_memory [1000, 128] f32
//   out: scalar f32
// Downsample 512->128 nearest picks rows/cols 4i, 4j exactly.
//
// NOTE (R3 post-mortem): cooperative grid.sync() costs ~60us/sync on MI355X
// (512 blocks, cross-XCD). Multi-dispatch with graph capture is far cheaper.

#define NPOS  131072   // 8*128*128
#define NBLK  512      // NPOS / 256
#define MEMSZ 1000
#define KANC  100      // MEM/10
#define KPN   333      // MEM/3
#define SLOT_POS 100
#define SLOT_NEG 433
#define NSLOTS 766
#define FIX_SCALE 1099511627776.0        // 2^40
#define INV_FIX   (1.0 / 1099511627776.0)

// ---------------- K1: argmax + masks + per-block ballot counts ----------------
__global__ __launch_bounds__(256) void mask_kernel(
    const float* __restrict__ preds,
    const int* __restrict__ fsss,
    uint8_t* __restrict__ flags,
    int* __restrict__ blockCounts)
{
    const int tid = threadIdx.x, blk = blockIdx.x;
    const int lane = tid & 63, wave = tid >> 6;
    const int n = blk * 256 + tid;
    const int b = n >> 14;
    const int ij = n & 16383;
    const int row = (ij >> 7) << 2;
    const int col = (ij & 127) << 2;

    const float* p = preds + (size_t)b * 21 * 262144 + (size_t)row * 512 + col;
    float best = p[0];
    int bc = 0;
#pragma unroll
    for (int c = 1; c < 21; ++c) {
        float v = p[(size_t)c * 262144];
        if (v > best) { best = v; bc = c; }   // strict > = first-max (jnp.argmax)
    }
    const int fv = fsss[(size_t)b * 262144 + (size_t)row * 512 + col];

    const bool pm = (bc != 0);
    const bool fm = (fv != 0) && (fv != 255);
    const int myflag = (int)(pm && fm)                // bit0: anchor
                     | ((int)(!pm && fm) << 1)        // bit1: positive
                     | ((int)(pm && (fv == 0)) << 2); // bit2: negative
    flags[n] = (uint8_t)myflag;

    __shared__ int s_i[12];
#pragma unroll
    for (int cat = 0; cat < 3; ++cat) {
        unsigned long long m = __ballot((myflag >> cat) & 1);
        if (lane == 0) s_i[cat * 4 + wave] = (int)__popcll(m);
    }
    __syncthreads();
    if (tid < 3)
        blockCounts[tid * NBLK + blk] =
            s_i[tid * 4] + s_i[tid * 4 + 1] + s_i[tid * 4 + 2] + s_i[tid * 4 + 3];
}

// ------- K2: per-block redundant prefix + first-k select + accum zeroing -------
__global__ __launch_bounds__(256) void select_kernel(
    const uint8_t* __restrict__ flags,
    const int* __restrict__ blockCounts,
    int* __restrict__ idx,
    int* __restrict__ totals,
    unsigned long long* __restrict__ accum)   // [4 shadows][3 cats][128]
{
    const int tid = threadIdx.x, blk = blockIdx.x;
    const int lane = tid & 63, wave = tid >> 6;
    __shared__ int s_i[12];

    // --- prefix over blocks < blk (counts table is 6KB, L2-resident) ---
#pragma unroll
    for (int cat = 0; cat < 3; ++cat) {
        const int c0 = blockCounts[cat * NBLK + tid];
        const int c1 = blockCounts[cat * NBLK + 256 + tid];
        int v = ((tid < blk) ? c0 : 0) + ((256 + tid < blk) ? c1 : 0);
#pragma unroll
        for (int off = 1; off < 64; off <<= 1) v += __shfl_xor(v, off, 64);
        if (lane == 0) s_i[cat * 4 + wave] = v;
    }
    __syncthreads();
    int pre[3];
#pragma unroll
    for (int cat = 0; cat < 3; ++cat)
        pre[cat] = s_i[cat * 4] + s_i[cat * 4 + 1] + s_i[cat * 4 + 2] + s_i[cat * 4 + 3];
    if (blk == NBLK - 1 && tid < 3)
        totals[tid] = pre[tid] + blockCounts[tid * NBLK + NBLK - 1];

    // block 0 zeroes the fixed-point accumulators (consumed by K3 next dispatch)
    if (blk == 0)
        for (int i = tid; i < 4 * 3 * 128; i += 256) accum[i] = 0ull;

    __syncthreads();   // s_i reuse below

    // --- first-k selection via ballots ---
    const int n = blk * 256 + tid;
    const int f = flags[n];
    unsigned long long masks[3];
#pragma unroll
    for (int cat = 0; cat < 3; ++cat) {
        masks[cat] = __ballot((f >> cat) & 1);
        if (lane == 0) s_i[cat * 4 + wave] = (int)__popcll(masks[cat]);
    }
    __syncthreads();
    const int kcap[3] = {KANC, KPN, KPN};
    const int basec[3] = {0, SLOT_POS, SLOT_NEG};
#pragma unroll
    for (int cat = 0; cat < 3; ++cat) {
        if ((f >> cat) & 1) {
            int woff = 0;
#pragma unroll
            for (int w = 0; w < 4; ++w) if (w < wave) woff += s_i[cat * 4 + w];
            const int intra = woff + (int)__popcll(masks[cat] & ((1ull << lane) - 1ull));
            const int rank = pre[cat] + intra;
            if (rank < kcap[cat]) idx[basec[cat] + rank] = n;
        }
    }
}

// ------ K3: gather+normalize selected rows -> fixed-point shadow accumulators ------
// blocks 0..382: 2 slots each.  blocks 383..398: memory-row tails.
__global__ __launch_bounds__(256) void gather_kernel(
    const float* __restrict__ emb,
    const float* __restrict__ posMem,
    const float* __restrict__ negMem,
    const int* __restrict__ idx,
    const int* __restrict__ totals,
    unsigned long long* __restrict__ accum)
{
    const int tid = threadIdx.x, blk = blockIdx.x;
    const int lane = tid & 63, wave = tid >> 6;
    const int d = tid & 127;
    const int A = min(KANC, totals[0]);
    const int P = min(KPN, totals[1]);
    const int Q = min(KPN, totals[2]);

    if (blk < 383) {
        const int half = tid >> 7;
        const int slot = blk * 2 + half;      // 0..765
        int cat; bool valid;
        if (slot < SLOT_POS)      { cat = 0; valid = slot < A; }
        else if (slot < SLOT_NEG) { cat = 1; valid = (slot - SLOT_POS) < P; }
        else                      { cat = 2; valid = (slot - SLOT_NEG) < Q; }

        float v = 0.f;
        if (valid) {
            const int nn = idx[slot];
            v = emb[((size_t)(nn >> 14) * 128 + d) * 16384 + (nn & 16383)];
        }
        float sq = v * v;
#pragma unroll
        for (int off = 1; off < 64; off <<= 1) sq += __shfl_xor(sq, off, 64);
        __shared__ float s_f[4];
        if (lane == 0) s_f[wave] = sq;
        __syncthreads();
        const float nrm2 = s_f[half * 2] + s_f[half * 2 + 1];
        if (valid) {
            const float scale = 1.0f / fmaxf(sqrtf(nrm2), 1e-12f);
            const double val = (double)v * (double)scale;
            const long long fx = (long long)llrint(val * FIX_SCALE);
            atomicAdd(&accum[(((size_t)(blk & 3) * 3 + cat) << 7) + d],
                      (unsigned long long)fx);
        }
    } else {
        const int t = blk - 383;
        const int memSel = t >> 3;            // 0=pos, 1=neg
        const int part = t & 7;
        const float* mem = memSel ? negMem : posMem;
        const int cnt = memSel ? Q : P;       // rows [0,cnt) were replaced
        const int rowHalf = tid >> 7;
        const int m0 = part * 125;
        double acc = 0.0;
        for (int r = rowHalf; r < 125; r += 2) {
            const int m = m0 + r;
            if (m >= cnt) acc += (double)mem[(size_t)m * 128 + d];
        }
        const long long fx = (long long)llrint(acc * FIX_SCALE);
        atomicAdd(&accum[(((size_t)(blk & 3) * 3 + (memSel ? 2 : 1)) << 7) + d],
                  (unsigned long long)fx);
    }
}

// ---------------- K4: final dot + relu (1 block, 128 threads) ----------------
__global__ __launch_bounds__(128) void final_kernel(
    const unsigned long long* __restrict__ accum,
    const int* __restrict__ totals,
    float* __restrict__ out)
{
    const int d = threadIdx.x;
    const int lane = d & 63, wave = d >> 6;
    double anc = 0.0, pos = 0.0, neg = 0.0;
#pragma unroll
    for (int s = 0; s < 4; ++s) {
        anc += (double)(long long)accum[((s * 3 + 0) << 7) + d];
        pos += (double)(long long)accum[((s * 3 + 1) << 7) + d];
        neg += (double)(long long)accum[((s * 3 + 2) << 7) + d];
    }
    double prod = anc * (pos - neg) * (INV_FIX * INV_FIX);
#pragma unroll
    for (int off = 1; off < 64; off <<= 1) prod += __shfl_xor(prod, off, 64);
    __shared__ double s_d[2];
    if (lane == 0) s_d[wave] = prod;
    __syncthreads();
    if (d == 0) {
        const double red = s_d[0] + s_d[1];
        const int A = min(KANC, totals[0]);
        const double nAnc = (A > 0) ? (double)A : 1.0;
        const double vv = red / (nAnc * (double)MEMSZ) + 0.2;
        out[0] = (float)(vv > 0.0 ? vv : 0.0);
    }
}

extern "C" void kernel_launch(void* const* d_in, const int* in_sizes, int n_in,
                              void* d_out, int out_size, void* d_ws, size_t ws_size,
                              hipStream_t stream) {
    const float* preds  = (const float*)d_in[0];
    const float* emb    = (const float*)d_in[1];
    // d_in[2] = gts, unused by the loss
    const int* fsss     = (const int*)d_in[3];
    const float* posMem = (const float*)d_in[4];
    const float* negMem = (const float*)d_in[5];
    float* out = (float*)d_out;

    char* ws = (char*)d_ws;
    uint8_t* flags   = (uint8_t*)ws;                       // 131072 B
    int* blockCounts = (int*)(ws + 131072);                // 3*512
    int* idx         = blockCounts + 3 * NBLK;             // 768
    int* totals      = idx + 768;                          // 4
    unsigned long long* accum =
        (unsigned long long*)(ws + 131072 + (3 * NBLK + 768 + 4) * 4 + 4); // align 8
    accum = (unsigned long long*)(((uintptr_t)accum + 7) & ~(uintptr_t)7);

    mask_kernel  <<<NBLK, 256, 0, stream>>>(preds, fsss, flags, blockCounts);
    select_kernel<<<NBLK, 256, 0, stream>>>(flags, blockCounts, idx, totals, accum);
    gather_kernel<<<399, 256, 0, stream>>>(emb, posMem, negMem, idx, totals, accum);
    final_kernel <<<1, 128, 0, stream>>>(accum, totals, out);
}